// Round 1
// baseline (294.359 us; speedup 1.0000x reference)
//
#include <hip/hip_runtime.h>
#include <hip/hip_bf16.h>

// LSTM cell fused kernel for MI355X (gfx950).
// B=65536, H=256. One packed GEMM [B,256]x[256,1024] in bf16 MFMA + fused gates.

typedef __attribute__((ext_vector_type(8))) short short8;   // 8 bf16 (4 VGPRs)
typedef __attribute__((ext_vector_type(4))) float f32x4;    // MFMA accumulator

static constexpr int Bsz  = 65536;
static constexpr int Hdim = 256;

// float -> bf16 bits, round-to-nearest-even (pure integer, no type-system risk)
__device__ __forceinline__ short f2bf(float f) {
    unsigned u = __float_as_uint(f);
    unsigned r = (u + 0x7FFFu + ((u >> 16) & 1u)) >> 16;
    return (short)r;
}

__device__ __forceinline__ float sigm(float x) {
    return 1.0f / (1.0f + __expf(-x));
}
__device__ __forceinline__ float tanh_fast(float x) {
    return 2.0f / (1.0f + __expf(-2.0f * x)) - 1.0f;
}

// ---------------------------------------------------------------------------
// Prep: pack Wf,Wc,Wi,Wo ([256,256] fp32, row j = output neuron, col k = input)
// into bf16 B-fragment-major layout for mfma_f32_16x16x32_bf16:
//   flat o = (((g*8 + ks)*16 + jf)*64 + lane)*8 + e
//   k = ks*32 + (lane>>4)*8 + e ;  j = jf*16 + (lane&15) ;  B[k][j] = W_g[j][k]
// Total 4*256*256 bf16 = 512 KB in d_ws (L2-resident during the main GEMM).
// ---------------------------------------------------------------------------
__global__ void __launch_bounds__(256)
prep_w_kernel(const float* __restrict__ Wf, const float* __restrict__ Wc,
              const float* __restrict__ Wi, const float* __restrict__ Wo,
              short* __restrict__ Bp)
{
    int o    = blockIdx.x * 256 + threadIdx.x;   // 0 .. 262143
    int e    = o & 7;
    int lane = (o >> 3) & 63;
    int jf   = (o >> 9) & 15;
    int ks   = (o >> 13) & 7;
    int g    = (o >> 16) & 3;
    int k = ks * 32 + (lane >> 4) * 8 + e;
    int j = jf * 16 + (lane & 15);
    const float* W = (g == 0) ? Wf : (g == 1) ? Wc : (g == 2) ? Wi : Wo;
    Bp[o] = f2bf(W[j * 256 + k]);
}

// ---------------------------------------------------------------------------
// Main fused kernel. Block = 64 rows x (all 1024 packed cols). 512 threads.
// Wave w (2x4 grid): rows [(w>>2)*32,+32), per-gate cols [(w&3)*64,+64),
// all 4 gates in-register => epilogue has every gate for (row,j) in one lane.
// ---------------------------------------------------------------------------
__global__ void __launch_bounds__(512, 2)
lstm_fused(const float* __restrict__ inp, const float* __restrict__ hid,
           const float* __restrict__ cell, const short* __restrict__ Bp,
           const float* __restrict__ bfv, const float* __restrict__ bcv,
           const float* __restrict__ biv, const float* __restrict__ bov,
           float* __restrict__ out)
{
    __shared__ short As[64 * 256];   // 32 KB bf16 combine tile, XOR-swizzled rows

    const int tid  = threadIdx.x;
    const int lane = tid & 63;
    const int wave = tid >> 6;
    const int row0 = blockIdx.x * 64;

    // ---- stage combine = input + hidden (bf16) into LDS -------------------
    // 2048 chunks of 8 elems; coalesced float4 global loads, ds_write_b128.
#pragma unroll
    for (int it = 0; it < 4; ++it) {
        int c   = tid + it * 512;        // chunk id 0..2047
        int row = c >> 5;                // 0..63
        int k0  = (c & 31) * 8;          // 0..248
        const float4* ip = reinterpret_cast<const float4*>(inp + (size_t)(row0 + row) * Hdim + k0);
        const float4* hp = reinterpret_cast<const float4*>(hid + (size_t)(row0 + row) * Hdim + k0);
        float4 a0 = ip[0], a1 = ip[1];
        float4 h0 = hp[0], h1 = hp[1];
        short8 v;
        v[0] = f2bf(a0.x + h0.x);
        v[1] = f2bf(a0.y + h0.y);
        v[2] = f2bf(a0.z + h0.z);
        v[3] = f2bf(a0.w + h0.w);
        v[4] = f2bf(a1.x + h1.x);
        v[5] = f2bf(a1.y + h1.y);
        v[6] = f2bf(a1.z + h1.z);
        v[7] = f2bf(a1.w + h1.w);
        int byte = row * 512 + k0 * 2;
        byte ^= (row & 7) << 4;          // bank-conflict swizzle (G4)
        *reinterpret_cast<short8*>(reinterpret_cast<char*>(As) + byte) = v;
    }
    __syncthreads();

    const int wrow = wave >> 2;          // 0..1
    const int wcol = wave & 3;           // 0..3
    const int r0w  = wrow * 32;          // block-local row base
    const int j0   = wcol * 64;          // per-gate col base
    const int lm   = lane & 15;
    const int lk   = lane >> 4;

    f32x4 acc[4][2][4];                  // [gate][m_frag][j_frag] = 128 VGPRs
#pragma unroll
    for (int g = 0; g < 4; ++g)
#pragma unroll
        for (int mf = 0; mf < 2; ++mf)
#pragma unroll
            for (int jf = 0; jf < 4; ++jf)
                acc[g][mf][jf] = (f32x4){0.f, 0.f, 0.f, 0.f};

    // ---- GEMM main loop: K=256 in 8 steps of 32 ---------------------------
#pragma unroll
    for (int ks = 0; ks < 8; ++ks) {
        short8 a[2];
#pragma unroll
        for (int mf = 0; mf < 2; ++mf) {
            int row  = r0w + mf * 16 + lm;
            int byte = row * 512 + (ks * 32 + lk * 8) * 2;
            byte ^= (row & 7) << 4;
            a[mf] = *reinterpret_cast<const short8*>(
                        reinterpret_cast<const char*>(As) + byte);
        }
#pragma unroll
        for (int g = 0; g < 4; ++g) {
#pragma unroll
            for (int jf = 0; jf < 4; ++jf) {
                int chunk = (g * 8 + ks) * 16 + (wcol * 4 + jf);
                short8 b = *reinterpret_cast<const short8*>(Bp + ((size_t)chunk * 64 + lane) * 8);
                acc[g][0][jf] = __builtin_amdgcn_mfma_f32_16x16x32_bf16(a[0], b, acc[g][0][jf], 0, 0, 0);
                acc[g][1][jf] = __builtin_amdgcn_mfma_f32_16x16x32_bf16(a[1], b, acc[g][1][jf], 0, 0, 0);
            }
        }
    }

    // ---- epilogue: gates + cell/hidden state, direct fp32 stores ----------
    float* out0 = out;                               // out (output gate)
    float* out1 = out + (size_t)Bsz * Hdim;          // hidden_state
    float* out2 = out + (size_t)2 * Bsz * Hdim;      // cell_state

#pragma unroll
    for (int jf = 0; jf < 4; ++jf) {
        int j = j0 + jf * 16 + lm;                   // 0..255 within gate
        float vbf = bfv[j], vbc = bcv[j], vbi = biv[j], vbo = bov[j];
#pragma unroll
        for (int mf = 0; mf < 2; ++mf) {
#pragma unroll
            for (int r = 0; r < 4; ++r) {
                int row = row0 + r0w + mf * 16 + lk * 4 + r;   // C/D: row=(lane>>4)*4+reg
                size_t off = (size_t)row * Hdim + j;
                float F = sigm(acc[0][mf][jf][r] + vbf);
                float C = tanh_fast(acc[1][mf][jf][r] + vbc);
                float I = sigm(sigm(acc[2][mf][jf][r] + vbi));  // double sigmoid, per ref
                float O = sigm(acc[3][mf][jf][r] + vbo);
                float cs = cell[off] * F + C * I;
                float hs = O * tanh_fast(cs);
                out0[off] = O;
                out1[off] = hs;
                out2[off] = cs;
            }
        }
    }
}

extern "C" void kernel_launch(void* const* d_in, const int* in_sizes, int n_in,
                              void* d_out, int out_size, void* d_ws, size_t ws_size,
                              hipStream_t stream)
{
    const float* inp  = (const float*)d_in[0];
    const float* hid  = (const float*)d_in[1];
    const float* cell = (const float*)d_in[2];
    const float* Wf   = (const float*)d_in[3];
    const float* bf_  = (const float*)d_in[4];
    const float* Wc   = (const float*)d_in[5];
    const float* bc_  = (const float*)d_in[6];
    const float* Wi   = (const float*)d_in[7];
    const float* bi_  = (const float*)d_in[8];
    const float* Wo   = (const float*)d_in[9];
    const float* bo_  = (const float*)d_in[10];

    short* Bp = (short*)d_ws;    // 512 KB packed bf16 weights

    prep_w_kernel<<<1024, 256, 0, stream>>>(Wf, Wc, Wi, Wo, Bp);
    lstm_fused<<<Bsz / 64, 512, 0, stream>>>(inp, hid, cell, Bp,
                                             bf_, bc_, bi_, bo_, (float*)d_out);
}

// Round 2
// 147.886 us; speedup vs baseline: 1.9904x; 1.9904x over previous
//
#include <hip/hip_runtime.h>
#include <hip/hip_bf16.h>

// LSTM cell fused kernel for MI355X (gfx950).
// B=65536, H=256. One packed GEMM [B,256]x[256,1024] in bf16 MFMA + fused gates.
// R2: occupancy fix — wave tile 32x32x4gates (64 acc regs), launch_bounds(512,4),
//     2 resident blocks/CU, cell preloaded into regs.

typedef __attribute__((ext_vector_type(8))) short short8;   // 8 bf16 (4 VGPRs)
typedef __attribute__((ext_vector_type(4))) float f32x4;    // MFMA accumulator

static constexpr int Bsz  = 65536;
static constexpr int Hdim = 256;

// float -> bf16 bits, round-to-nearest-even
__device__ __forceinline__ short f2bf(float f) {
    unsigned u = __float_as_uint(f);
    unsigned r = (u + 0x7FFFu + ((u >> 16) & 1u)) >> 16;
    return (short)r;
}

__device__ __forceinline__ float sigm(float x) {
    return 1.0f / (1.0f + __expf(-x));
}
__device__ __forceinline__ float tanh_fast(float x) {
    return 2.0f / (1.0f + __expf(-2.0f * x)) - 1.0f;
}

// ---------------------------------------------------------------------------
// Prep: pack Wf,Wc,Wi,Wo ([256,256] fp32) into bf16 B-fragment-major layout
// for mfma_f32_16x16x32_bf16:
//   flat o = (((g*8 + ks)*16 + jf)*64 + lane)*8 + e
//   k = ks*32 + (lane>>4)*8 + e ;  j = jf*16 + (lane&15) ;  B[k][j] = W_g[j][k]
// 512 KB in d_ws, L2-resident during the main GEMM.
// ---------------------------------------------------------------------------
__global__ void __launch_bounds__(256)
prep_w_kernel(const float* __restrict__ Wf, const float* __restrict__ Wc,
              const float* __restrict__ Wi, const float* __restrict__ Wo,
              short* __restrict__ Bp)
{
    int o    = blockIdx.x * 256 + threadIdx.x;   // 0 .. 262143
    int e    = o & 7;
    int lane = (o >> 3) & 63;
    int jf   = (o >> 9) & 15;
    int ks   = (o >> 13) & 7;
    int g    = (o >> 16) & 3;
    int k = ks * 32 + (lane >> 4) * 8 + e;
    int j = jf * 16 + (lane & 15);
    const float* W = (g == 0) ? Wf : (g == 1) ? Wc : (g == 2) ? Wi : Wo;
    Bp[o] = f2bf(W[j * 256 + k]);
}

// ---------------------------------------------------------------------------
// Main fused kernel. Block = 32 rows x all 1024 packed cols. 512 threads.
// All 8 waves share the 32 rows; wave w owns gate-cols [w*32, w*32+32) for
// ALL 4 gates => epilogue has every gate for (row,j) in one lane, no exchange.
// acc[4][2][2] = 64 VGPRs -> ~120 total regs -> 4 waves/SIMD, 2 blocks/CU.
// ---------------------------------------------------------------------------
__global__ void __launch_bounds__(512, 4)
lstm_fused(const float* __restrict__ inp, const float* __restrict__ hid,
           const float* __restrict__ cell, const short* __restrict__ Bp,
           const float* __restrict__ bfv, const float* __restrict__ bcv,
           const float* __restrict__ biv, const float* __restrict__ bov,
           float* __restrict__ out)
{
    __shared__ short As[32 * 256];   // 16 KB bf16 combine tile, XOR-swizzled rows

    const int tid  = threadIdx.x;
    const int lane = tid & 63;
    const int wave = tid >> 6;
    const int row0 = blockIdx.x * 32;

    // ---- stage combine = input + hidden (bf16) into LDS -------------------
    // 1024 chunks of 8 elems; 512 threads -> 2 chunks each.
#pragma unroll
    for (int it = 0; it < 2; ++it) {
        int c   = tid + it * 512;        // chunk id 0..1023
        int row = c >> 5;                // 0..31
        int k0  = (c & 31) * 8;          // 0..248
        const float4* ip = reinterpret_cast<const float4*>(inp + (size_t)(row0 + row) * Hdim + k0);
        const float4* hp = reinterpret_cast<const float4*>(hid + (size_t)(row0 + row) * Hdim + k0);
        float4 a0 = ip[0], a1 = ip[1];
        float4 h0 = hp[0], h1 = hp[1];
        short8 v;
        v[0] = f2bf(a0.x + h0.x);
        v[1] = f2bf(a0.y + h0.y);
        v[2] = f2bf(a0.z + h0.z);
        v[3] = f2bf(a0.w + h0.w);
        v[4] = f2bf(a1.x + h1.x);
        v[5] = f2bf(a1.y + h1.y);
        v[6] = f2bf(a1.z + h1.z);
        v[7] = f2bf(a1.w + h1.w);
        int byte = row * 512 + k0 * 2;
        byte ^= (row & 7) << 4;          // bank-conflict swizzle
        *reinterpret_cast<short8*>(reinterpret_cast<char*>(As) + byte) = v;
    }
    __syncthreads();

    const int j0 = wave * 32;            // per-gate col base for this wave
    const int lm = lane & 15;
    const int lk = lane >> 4;

    f32x4 acc[4][2][2];                  // [gate][m_frag][j_frag] = 64 VGPRs
#pragma unroll
    for (int g = 0; g < 4; ++g)
#pragma unroll
        for (int mf = 0; mf < 2; ++mf)
#pragma unroll
            for (int jf = 0; jf < 2; ++jf)
                acc[g][mf][jf] = (f32x4){0.f, 0.f, 0.f, 0.f};

    // ---- GEMM main loop: K=256 in 8 steps of 32 ---------------------------
#pragma unroll
    for (int ks = 0; ks < 8; ++ks) {
        short8 a[2];
#pragma unroll
        for (int mf = 0; mf < 2; ++mf) {
            int row  = mf * 16 + lm;
            int byte = row * 512 + (ks * 32 + lk * 8) * 2;
            byte ^= (row & 7) << 4;
            a[mf] = *reinterpret_cast<const short8*>(
                        reinterpret_cast<const char*>(As) + byte);
        }
#pragma unroll
        for (int g = 0; g < 4; ++g) {
#pragma unroll
            for (int jf = 0; jf < 2; ++jf) {
                int chunk = (g * 8 + ks) * 16 + (wave * 2 + jf);
                short8 b = *reinterpret_cast<const short8*>(Bp + ((size_t)chunk * 64 + lane) * 8);
                acc[g][0][jf] = __builtin_amdgcn_mfma_f32_16x16x32_bf16(a[0], b, acc[g][0][jf], 0, 0, 0);
                acc[g][1][jf] = __builtin_amdgcn_mfma_f32_16x16x32_bf16(a[1], b, acc[g][1][jf], 0, 0, 0);
            }
        }
    }

    // ---- epilogue: gates + cell/hidden state, direct fp32 stores ----------
    float* out0 = out;                               // out (output gate)
    float* out1 = out + (size_t)Bsz * Hdim;          // hidden_state
    float* out2 = out + (size_t)2 * Bsz * Hdim;      // cell_state

    // preload cell values (16 independent loads in flight)
    float cv[2][2][4];
#pragma unroll
    for (int mf = 0; mf < 2; ++mf)
#pragma unroll
        for (int jf = 0; jf < 2; ++jf)
#pragma unroll
            for (int r = 0; r < 4; ++r) {
                int row = row0 + mf * 16 + lk * 4 + r;
                int j   = j0 + jf * 16 + lm;
                cv[mf][jf][r] = cell[(size_t)row * Hdim + j];
            }

#pragma unroll
    for (int jf = 0; jf < 2; ++jf) {
        int j = j0 + jf * 16 + lm;                   // 0..255 within gate
        float vbf = bfv[j], vbc = bcv[j], vbi = biv[j], vbo = bov[j];
#pragma unroll
        for (int mf = 0; mf < 2; ++mf) {
#pragma unroll
            for (int r = 0; r < 4; ++r) {
                int row = row0 + mf * 16 + lk * 4 + r;   // C/D: row=(lane>>4)*4+reg
                size_t off = (size_t)row * Hdim + j;
                float F = sigm(acc[0][mf][jf][r] + vbf);
                float C = tanh_fast(acc[1][mf][jf][r] + vbc);
                float I = sigm(sigm(acc[2][mf][jf][r] + vbi));  // double sigmoid, per ref
                float O = sigm(acc[3][mf][jf][r] + vbo);
                float cs = cv[mf][jf][r] * F + C * I;
                float hs = O * tanh_fast(cs);
                out0[off] = O;
                out1[off] = hs;
                out2[off] = cs;
            }
        }
    }
}

extern "C" void kernel_launch(void* const* d_in, const int* in_sizes, int n_in,
                              void* d_out, int out_size, void* d_ws, size_t ws_size,
                              hipStream_t stream)
{
    const float* inp  = (const float*)d_in[0];
    const float* hid  = (const float*)d_in[1];
    const float* cell = (const float*)d_in[2];
    const float* Wf   = (const float*)d_in[3];
    const float* bf_  = (const float*)d_in[4];
    const float* Wc   = (const float*)d_in[5];
    const float* bc_  = (const float*)d_in[6];
    const float* Wi   = (const float*)d_in[7];
    const float* bi_  = (const float*)d_in[8];
    const float* Wo   = (const float*)d_in[9];
    const float* bo_  = (const float*)d_in[10];

    short* Bp = (short*)d_ws;    // 512 KB packed bf16 weights

    prep_w_kernel<<<1024, 256, 0, stream>>>(Wf, Wc, Wi, Wo, Bp);
    lstm_fused<<<Bsz / 32, 512, 0, stream>>>(inp, hid, cell, Bp,
                                             bf_, bc_, bi_, bo_, (float*)d_out);
}